// Round 8
// baseline (1158.618 us; speedup 1.0000x reference)
//
#include <hip/hip_runtime.h>
#include <hip/hip_bf16.h>
#include <cstdint>

// Neural ODE: 10 Heun steps of f(y) = tanh(y@W1 + b1)@W2 + b2
// BATCH=8192, D=512, H=2048, dt=0.1
// R14 = R13 (32x32x16 MFMA, 56.6us/eval) + ILP restructure:
//  - 512 threads / 8 waves, launch_bounds(512,2) -> 256 VGPR budget.
//  - 2 n-tiles per wave in BOTH GEMMs -> each A ds_read feeds 2 MFMAs
//    (LDS pipe 49K -> 24.5K cyc/CU/eval).
//  - B-frag loads register-batched 16-deep and double-buffered across
//    half-chunks: 16-32 outstanding vmem loads per wave hide L2 latency
//    structurally (R11's 1-deep rotation was folded by the allocator at
//    the 128-VGPR cap; at 256 there is no pressure to fold).
// Budget at R13: L2 weight stream ~70K cyc (51%), LDS 49K (36%), MFMA 33K
// (25%), VALU 31K (23%); wall 136K => overlap factor 1.36. This round
// pushes the wall toward the ~70K-cyc (29us) L2 stream floor.
// Verification hook: VGPR must land ~190-220 (else the batch was folded).
// Dead axes: R7 reg-resident A (remat), R8 serialized scatter, R10
// CW512@16x16, R11 1-deep prefetch (folded), R12 wave specialization.

#define BATCHN 8192
#define DDIM 512
#define HDIM 2048
#define CW 512          // chunk width over H
#define NCH (HDIM / CW) // 4

typedef short short8 __attribute__((ext_vector_type(8)));
typedef float floatx16 __attribute__((ext_vector_type(16)));

__device__ __forceinline__ unsigned short f2bf(float f) {
  union { __hip_bfloat16 h; unsigned short u; } cv;
  cv.h = __float2bfloat16(f);
  return cv.u;
}

__device__ __forceinline__ float fast_tanh(float x) {
  float e = __expf(2.0f * x);
  return 1.0f - 2.0f / (e + 1.0f);
}

__device__ __forceinline__ void glds16(const void* g, void* l) {
  __builtin_amdgcn_global_load_lds(
      (const __attribute__((address_space(1))) void*)(uintptr_t)g,
      (__attribute__((address_space(3))) void*)(uint32_t)(uintptr_t)l,
      16, 0, 0);
}

// 32x32x16 fragment conventions (verified by R13 passing):
//  A-frag: lane holds A[m = lane&31][k = (lane>>5)*8 + j], j=0..7 (16B)
//  B-frag: lane holds B[n = lane&31][k = (lane>>5)*8 + j]   (BT row-major)
//  C/D:    col = lane&31, row = (reg&3) + 8*(reg>>2) + 4*(lane>>5)
// Packed buffers: frag f stored at [(f*64 + lane)*8] halves.
//  yPack: f = rb*32 + ks   (rb = batch-row/32: 0..255, ks = D k-step: 0..31)
//  w1p:   f = nb*32 + kb   (nb = H col-tile/32: 0..63,  kb = D k-step: 0..31)
//  w2p:   f = nb*128 + kb  (nb = D col-tile/32: 0..15,  kb = H k-step: 0..127)

__global__ __launch_bounds__(512, 2) void fused_feval(
    const unsigned short* __restrict__ yPack,   // packed bf16 eval input
    const unsigned short* __restrict__ w1p,
    const unsigned short* __restrict__ w2p,
    const float* __restrict__ b1,
    const float* __restrict__ b2,
    const float* __restrict__ stateIn,   // EPI1: y fp32 ; EPI2: p fp32
    float* __restrict__ stateOut,        // EPI1: p      ; EPI2: ynew
    unsigned short* __restrict__ outPack,// packed bf16 next-eval input
    int epi) {                           // 1 or 2
  __shared__ unsigned short yA[32 * 512];       // 32 KB, A32 frags ks=0..31
  __shared__ unsigned short hA[2][32 * 512];    // 2 x 32 KB, A32 frags/chunk

  const int tid  = threadIdx.x;
  const int lane = tid & 63;
  const int w    = tid >> 6;    // wave 0..7
  const int c31  = lane & 31;
  const int lhi  = lane >> 5;   // 0..1
  const int blk  = blockIdx.x;  // 0..255
  const int B0   = blk * 32;    // slab base row

  // phase0: linear copy of this block's 32 KB packed y-slab into LDS.
  {
    const unsigned short* src = yPack + (size_t)blk * (32 * 512);
#pragma unroll
    for (int p = 0; p < 4; ++p)
      glds16(src + (size_t)(p * 512 + tid) * 8, &yA[(p * 512 + tid) * 8]);
  }

  // preload per-chunk b1 biases for this wave's 2 n-tiles.
  float bb1v[NCH][2];
#pragma unroll
  for (int c = 0; c < NCH; ++c)
#pragma unroll
    for (int i = 0; i < 2; ++i)
      bb1v[c][i] = b1[c * CW + (w * 2 + i) * 32 + c31];

  __syncthreads();

  floatx16 accY[2] = {};  // GEMM2 acc: cols (w*2+i)*32 + c31

#pragma unroll
  for (int c = 0; c < NCH; ++c) {
    // ---- phase1: acc1[i] = y @ W1[:, (c*16 + w*2 + i)*32 ..] ----
    floatx16 acc1[2] = {};
    const unsigned short* w1b0 =
        w1p + ((size_t)((c * 16 + w * 2 + 0) * 32) * 64 + lane) * 8;
    const unsigned short* w1b1 =
        w1p + ((size_t)((c * 16 + w * 2 + 1) * 32) * 64 + lane) * 8;
    short8 bb[2][2][8];  // [buf][tile][k] — fully unrolled, static idx
#pragma unroll
    for (int k = 0; k < 8; ++k) {
      bb[0][0][k] = *(const short8*)(w1b0 + (size_t)k * 512);
      bb[0][1][k] = *(const short8*)(w1b1 + (size_t)k * 512);
    }
#pragma unroll
    for (int h = 0; h < 4; ++h) {
      const int cur = h & 1;
      if (h < 3) {
#pragma unroll
        for (int k = 0; k < 8; ++k) {
          bb[cur ^ 1][0][k] = *(const short8*)(w1b0 + (size_t)((h + 1) * 8 + k) * 512);
          bb[cur ^ 1][1][k] = *(const short8*)(w1b1 + (size_t)((h + 1) * 8 + k) * 512);
        }
      }
#pragma unroll
      for (int k = 0; k < 8; ++k) {
        short8 a = *(const short8*)&yA[((h * 8 + k) * 64 + lane) * 8];
        acc1[0] = __builtin_amdgcn_mfma_f32_32x32x16_bf16(a, bb[cur][0][k], acc1[0], 0, 0, 0);
        acc1[1] = __builtin_amdgcn_mfma_f32_32x32x16_bf16(a, bb[cur][1][k], acc1[1], 0, 0, 0);
      }
    }

    // bias + tanh + scatter into hA[c&1] (A32-frag layout, k = col in chunk)
    {
      unsigned short* hbuf = hA[c & 1];
#pragma unroll
      for (int i1 = 0; i1 < 2; ++i1) {
        const int kloc = (w * 2 + i1) * 32 + c31;  // lane's h-col in chunk
        const float bb1 = bb1v[c][i1];
        const int ksf = kloc >> 4;                 // frag 0..31
        const int lh  = (kloc >> 3) & 1;
        const int jj  = kloc & 7;
        const int mhi = lhi * 4;
#pragma unroll
        for (int reg = 0; reg < 16; ++reg) {
          const int m = (reg & 3) + 8 * (reg >> 2) + mhi;   // C/D row
          hbuf[(ksf * 64 + (m + 32 * lh)) * 8 + jj] =
              f2bf(fast_tanh(acc1[i1][reg] + bb1));
        }
      }
    }

    // ---- phase2 for chunk c-1: accY += h_prev @ W2-slice ----
    if (c > 0) {
      const int cc = c - 1;
      const unsigned short* hp = hA[cc & 1];
      const unsigned short* w2b0 =
          w2p + ((size_t)((w * 2 + 0) * 128 + cc * 32) * 64 + lane) * 8;
      const unsigned short* w2b1 =
          w2p + ((size_t)((w * 2 + 1) * 128 + cc * 32) * 64 + lane) * 8;
      short8 cb[2][2][8];
#pragma unroll
      for (int k = 0; k < 8; ++k) {
        cb[0][0][k] = *(const short8*)(w2b0 + (size_t)k * 512);
        cb[0][1][k] = *(const short8*)(w2b1 + (size_t)k * 512);
      }
#pragma unroll
      for (int h = 0; h < 4; ++h) {
        const int cur = h & 1;
        if (h < 3) {
#pragma unroll
          for (int k = 0; k < 8; ++k) {
            cb[cur ^ 1][0][k] = *(const short8*)(w2b0 + (size_t)((h + 1) * 8 + k) * 512);
            cb[cur ^ 1][1][k] = *(const short8*)(w2b1 + (size_t)((h + 1) * 8 + k) * 512);
          }
        }
#pragma unroll
        for (int k = 0; k < 8; ++k) {
          short8 a = *(const short8*)&hp[((h * 8 + k) * 64 + lane) * 8];
          accY[0] = __builtin_amdgcn_mfma_f32_32x32x16_bf16(a, cb[cur][0][k], accY[0], 0, 0, 0);
          accY[1] = __builtin_amdgcn_mfma_f32_32x32x16_bf16(a, cb[cur][1][k], accY[1], 0, 0, 0);
        }
      }
    }
    __syncthreads();
  }
  // tail phase2: chunk NCH-1 (buffer (NCH-1)&1 = 1)
  {
    const int cc = NCH - 1;
    const unsigned short* hp = hA[cc & 1];
    const unsigned short* w2b0 =
        w2p + ((size_t)((w * 2 + 0) * 128 + cc * 32) * 64 + lane) * 8;
    const unsigned short* w2b1 =
        w2p + ((size_t)((w * 2 + 1) * 128 + cc * 32) * 64 + lane) * 8;
    short8 cb[2][2][8];
#pragma unroll
    for (int k = 0; k < 8; ++k) {
      cb[0][0][k] = *(const short8*)(w2b0 + (size_t)k * 512);
      cb[0][1][k] = *(const short8*)(w2b1 + (size_t)k * 512);
    }
#pragma unroll
    for (int h = 0; h < 4; ++h) {
      const int cur = h & 1;
      if (h < 3) {
#pragma unroll
        for (int k = 0; k < 8; ++k) {
          cb[cur ^ 1][0][k] = *(const short8*)(w2b0 + (size_t)((h + 1) * 8 + k) * 512);
          cb[cur ^ 1][1][k] = *(const short8*)(w2b1 + (size_t)((h + 1) * 8 + k) * 512);
        }
      }
#pragma unroll
      for (int k = 0; k < 8; ++k) {
        short8 a = *(const short8*)&hp[((h * 8 + k) * 64 + lane) * 8];
        accY[0] = __builtin_amdgcn_mfma_f32_32x32x16_bf16(a, cb[cur][0][k], accY[0], 0, 0, 0);
        accY[1] = __builtin_amdgcn_mfma_f32_32x32x16_bf16(a, cb[cur][1][k], accY[1], 0, 0, 0);
      }
    }
  }
  __syncthreads();  // all waves done reading hA before reuse as pack staging

  // Epilogue: add b2, Heun combine with fp32 state, pack bf16 result.
  {
    unsigned short* pbuf = &hA[0][0];  // 32 KB staging, yPack A32 layout
#pragma unroll
    for (int i = 0; i < 2; ++i) {
      const int ncol = (w * 2 + i) * 32 + c31;  // 0..511
      const float bb = b2[ncol];
      const int ksf = ncol >> 4;
      const int lh  = (ncol >> 3) & 1;
      const int jj  = ncol & 7;
      const int mhi = lhi * 4;
#pragma unroll
      for (int reg = 0; reg < 16; ++reg) {
        const int mrow = (reg & 3) + 8 * (reg >> 2) + mhi;
        const int row = B0 + mrow;
        const size_t idx = (size_t)row * DDIM + ncol;
        const float v = accY[i][reg] + bb;
        float nv;
        if (epi == 1) {
          const float y = stateIn[idx];
          stateOut[idx] = y + 0.05f * v;   // p = y + (dt/2)*k1
          nv = y + 0.1f * v;               // ymid
        } else {
          const float yn = stateIn[idx] + 0.05f * v;  // ynew = p + (dt/2)*k2
          stateOut[idx] = yn;
          nv = yn;
        }
        pbuf[(ksf * 64 + (mrow + 32 * lh)) * 8 + jj] = f2bf(nv);
      }
    }
    __syncthreads();
    unsigned short* dst = outPack + (size_t)blk * (32 * 512);
#pragma unroll
    for (int p = 0; p < 4; ++p) {
      short8 v = *(const short8*)&pbuf[(size_t)(p * 512 + tid) * 8];
      *(short8*)&dst[(size_t)(p * 512 + tid) * 8] = v;
    }
  }
}

// Pack weight [K][N] fp32 -> 32x32 B-frag order: frag f = nb*KB + kb,
// lane entry = src[kb*16 + (lane>>5)*8 + j][nb*32 + (lane&31)].
__global__ void pack_b(const float* __restrict__ src, unsigned short* __restrict__ dst,
                       int KB, int N) {
  const int t = blockIdx.x * 256 + threadIdx.x;
  const int lane = t & 63, f = t >> 6;
  const int nb = f / KB, kb = f % KB;
  const int k0 = kb * 16 + (lane >> 5) * 8, n = nb * 32 + (lane & 31);
  short8 v;
#pragma unroll
  for (int j = 0; j < 8; ++j)
    v[j] = (short)f2bf(src[(size_t)(k0 + j) * N + n]);
  *(short8*)&dst[(size_t)t * 8] = v;
}

// y0 fp32 [8192][512] -> yF fp32 copy + packed bf16 32x32 A-frags.
// frag f = rb*32 + ks; lane entry = y0[rb*32 + (lane&31)][ks*16 + (lane>>5)*8 + j]
__global__ void pack_y(const float* __restrict__ y0, float* __restrict__ yF,
                       unsigned short* __restrict__ ypk) {
  const int t = blockIdx.x * 256 + threadIdx.x;
  const int lane = t & 63, f = t >> 6;
  const int rb = f >> 5, ks = f & 31;
  const int row = rb * 32 + (lane & 31), c0 = ks * 16 + (lane >> 5) * 8;
  short8 v;
#pragma unroll
  for (int j = 0; j < 8; ++j) {
    const float x = y0[(size_t)row * DDIM + c0 + j];
    yF[(size_t)row * DDIM + c0 + j] = x;
    v[j] = (short)f2bf(x);
  }
  *(short8*)&ypk[(size_t)t * 8] = v;
}

extern "C" void kernel_launch(void* const* d_in, const int* in_sizes, int n_in,
                              void* d_out, int out_size, void* d_ws, size_t ws_size,
                              hipStream_t stream) {
  const float* y0 = (const float*)d_in[0];
  const float* W1 = (const float*)d_in[1];  // [512][2048]
  const float* b1 = (const float*)d_in[2];  // [2048]
  const float* W2 = (const float*)d_in[3];  // [2048][512]
  const float* b2 = (const float*)d_in[4];  // [512]

  char* ws = (char*)d_ws;
  float*          yF   = (float*)(ws);                         // 16 MB
  float*          pF   = (float*)(ws + (size_t)(16u << 20));   // 16 MB
  unsigned short* ypk  = (unsigned short*)(ws + (size_t)(32u << 20)); // 8 MB
  unsigned short* ympk = (unsigned short*)(ws + (size_t)(40u << 20)); // 8 MB
  unsigned short* w1p  = (unsigned short*)(ws + (size_t)(48u << 20)); // 2 MB
  unsigned short* w2p  = (unsigned short*)(ws + (size_t)(50u << 20)); // 2 MB

  // Pre-pass: pack weights (2048 frags each) and y0 (8192 frags).
  pack_b<<<512, 256, 0, stream>>>(W1, w1p, 32, HDIM);
  pack_b<<<512, 256, 0, stream>>>(W2, w2p, 128, DDIM);
  pack_y<<<2048, 256, 0, stream>>>(y0, yF, ypk);

  const dim3 grid(256), blkd(512);
  for (int s = 0; s < 10; ++s) {
    // eval1: k1 = f(y); p = y + 0.05*k1; ymid = y + 0.1*k1 (packed)
    fused_feval<<<grid, blkd, 0, stream>>>(ypk, w1p, w2p, b1, b2, yF, pF, ympk, 1);
    // eval2: k2 = f(ymid); ynew = p + 0.05*k2 (fp32 + packed)
    float* yOut = (s == 9) ? (float*)d_out : yF;
    fused_feval<<<grid, blkd, 0, stream>>>(ympk, w1p, w2p, b1, b2, pF, yOut, ypk, 2);
  }
}